// Round 9
// baseline (189.138 us; speedup 1.0000x reference)
//
#include <hip/hip_runtime.h>

// ---------------------------------------------------------------------------
// SwitchGLU MoE, round 9: R8 schedule with stage2 K-coverage bug fixed.
//  - R8 bug: stage2 ran 16 K-steps x BK=32 with ks*512 -> covered only
//    K in [0,1024) of HDIM=2048. Fix: 32 K-steps, ks*1024. Stage1 unchanged.
//  - per K-step: 2 sub-phases {stage-issue || ds_read frags -> barrier ->
//    setprio(1) MFMA cluster setprio(0) -> barrier}; ONE counted vmcnt per
//    K-step (never 0 in steady state) -> prefetch flies across barriers.
//  - 3 LDS buffers, 2-step lookahead. 8 waves/block.
//  - x pre-converted to bf16 -> X stages/reads at bf16 width.
// ---------------------------------------------------------------------------

typedef unsigned short u16;
typedef unsigned int   u32;
typedef u16    u16x8 __attribute__((ext_vector_type(8)));
typedef __bf16 bf16x8 __attribute__((ext_vector_type(8)));
typedef float  f32x4 __attribute__((ext_vector_type(4)));

#define NE   8
#define DDIM 768
#define HDIM 2048
#define NTOT 2048
#define NTOK 1024   // B*S
#define MAXT 24

__device__ __forceinline__ u16 f2bf(float f) {
  return (u16)((__builtin_bit_cast(u32, f) + 0x8000u) >> 16);
}
__device__ __forceinline__ bf16x8 cvt8(float4 a, float4 b) {
  bf16x8 r;
  r[0] = (__bf16)a.x; r[1] = (__bf16)a.y; r[2] = (__bf16)a.z; r[3] = (__bf16)a.w;
  r[4] = (__bf16)b.x; r[5] = (__bf16)b.y; r[6] = (__bf16)b.z; r[7] = (__bf16)b.w;
  return r;
}
__device__ __forceinline__ f32x4 mfma(bf16x8 a, bf16x8 b, f32x4 c) {
  return __builtin_amdgcn_mfma_f32_16x16x32_bf16(a, b, c, 0, 0, 0);
}
__device__ __forceinline__ void gl16(const void* g, void* l) {
  __builtin_amdgcn_global_load_lds(
      (const __attribute__((address_space(1))) void*)g,
      (__attribute__((address_space(3))) void*)l, 16, 0, 0);
}
#define SCHEDB() __builtin_amdgcn_sched_barrier(0)
#define BAR()    __builtin_amdgcn_s_barrier()
#define PRIO(n)  __builtin_amdgcn_s_setprio(n)
#define VMW(n)   asm volatile("s_waitcnt vmcnt(" #n ")" ::: "memory")

// fp32 tile frag read: rows of 32 floats = 8 chunks of 16B, chunk ^= r&7
#define RD8(arr, o_, r_, kb_) cvt8(                                            \
    *(const float4*)&(arr)[(o_) + (r_) * 32 + ((((kb_)*2    ) ^ ((r_)&7)) << 2)], \
    *(const float4*)&(arr)[(o_) + (r_) * 32 + ((((kb_)*2 + 1) ^ ((r_)&7)) << 2)])
// bf16 tile frag read: rows of 32 u16 = 4 chunks of 16B, chunk ^= (r>>1)&3
#define RDB(arr, o_, r_, kb_) __builtin_bit_cast(bf16x8,                       \
    *(const u16x8*)&(arr)[(o_) + (r_) * 32 + (((kb_) ^ (((r_)>>1)&3)) << 3)])

// ---------------------------------------------------------------------------
// x (fp32, NTOK x DDIM) -> xb (bf16). 384 blocks x 256 thr x 8 elems.
// ---------------------------------------------------------------------------
__global__ __launch_bounds__(256) void moe_cvtx(const float* __restrict__ x,
                                                u16* __restrict__ xb) {
  const int i = (blockIdx.x * 256 + threadIdx.x) * 8;
  const float4 f0 = *(const float4*)(x + i);
  const float4 f1 = *(const float4*)(x + i + 4);
  *(uint4*)(xb + i) = __builtin_bit_cast(uint4, cvt8(f0, f1));
}

// ---------------------------------------------------------------------------
// Dispatch: bucket token-pairs by expert + 128-row tile table.
// ---------------------------------------------------------------------------
__global__ void moe_dispatch(const int* __restrict__ idx,
                             int* __restrict__ meta, int* __restrict__ perm) {
  __shared__ int s_cnt[NE];
  __shared__ int s_off[NE + 1];
  __shared__ int s_cur[NE];
  const int tid = threadIdx.x;
  if (tid < NE) { s_cnt[tid] = 0; s_cur[tid] = 0; }
  __syncthreads();
  for (int n = tid; n < NTOT; n += 256) atomicAdd(&s_cnt[idx[n]], 1);
  __syncthreads();
  if (tid == 0) {
    int a = 0;
    for (int e = 0; e < NE; ++e) { s_off[e] = a; a += s_cnt[e]; }
    s_off[NE] = a;
  }
  __syncthreads();
  for (int n = tid; n < NTOT; n += 256) {
    const int e = idx[n];
    perm[s_off[e] + atomicAdd(&s_cur[e], 1)] = n;
  }
  if (tid == 0) {
    int tc = 0;
    for (int e = 0; e < NE; ++e) {
      for (int r0 = s_off[e]; r0 < s_off[e + 1]; r0 += 128) {
        meta[16 + tc] = e;
        meta[48 + tc] = r0;
        ++tc;
      }
    }
    meta[15] = tc;
  }
  if (tid < NE + 1) meta[tid] = s_off[tid];
}

// ---------------------------------------------------------------------------
// Stage 1: h = silu(X Wg^T) * (X Wu^T).  BM=128, BN=128(G)+128(U), BK=32.
// grid = MAXT*16. 512 thr = 8 waves (2M x 4N); wave = 64M x 32N of both.
// LDS: Xb 8KB + G 16KB + U 16KB per buffer, x3 buffers = 120KB.
// 24 K-steps (24*32 = 768 = DDIM); 5 gl_lds/thread/step; steady vmcnt(5).
// ---------------------------------------------------------------------------
__global__ __launch_bounds__(512, 1) void moe_stage1(
    const u16* __restrict__ xb, const int* __restrict__ perm,
    const int* __restrict__ meta, const float* __restrict__ wg,
    const float* __restrict__ wu, u16* __restrict__ hbuf) {
  const int t = blockIdx.x >> 4;
  if (t >= meta[15]) return;
  const int nt = blockIdx.x & 15;  // H columns nt*128
  const int e = meta[16 + t];
  const int r0 = meta[48 + t];
  const int rows = min(128, meta[e + 1] - r0);

  __shared__ __align__(16) u16   sX[3 * 128 * 32];  // bf16
  __shared__ __align__(16) float sG[3 * 128 * 32];
  __shared__ __align__(16) float sU[3 * 128 * 32];

  const int tid = threadIdx.x;
  const int lane = tid & 63;
  const int wv = tid >> 6;
  const int wm = (wv >> 2) * 64;  // 0,64
  const int wn = (wv & 3) * 32;   // 0,32,64,96

  // X staging (bf16): 1 gl16/thread; instr covers 16 rows x 4 chunks
  const int xr = wv * 16 + (lane >> 2);
  const int tok = perm[r0 + min(xr, rows - 1)] >> 1;  // TOPK=2
  const u16* gpX = xb + (size_t)tok * DDIM + (((lane & 3) ^ ((xr >> 1) & 3)) << 3);
  const int lbX = wv * 16 * 32;
  // W staging (fp32): 2 gl16/thread each; instr covers 8 rows x 8 chunks
  const int lr = lane >> 3, lc = lane & 7;
  const float* gpG[2];
  const float* gpU[2];
  int lbW[2];
#pragma unroll
  for (int j = 0; j < 2; ++j) {
    const int r = wv * 16 + j * 8 + lr;
    const size_t row = (size_t)e * HDIM + nt * 128 + r;
    gpG[j] = wg + row * DDIM + ((lc ^ (r & 7)) << 2);
    gpU[j] = wu + row * DDIM + ((lc ^ (r & 7)) << 2);
    lbW[j] = (wv * 16 + j * 8) * 32;
  }

  f32x4 aG[4][2] = {};
  f32x4 aU[4][2] = {};

#define S1_STAGE_ALL(b) do {                                     \
    gl16(gpX, &sX[(b) * 4096 + lbX]);                            \
    gl16(gpG[0], &sG[(b) * 4096 + lbW[0]]);                      \
    gl16(gpG[1], &sG[(b) * 4096 + lbW[1]]);                      \
    gl16(gpU[0], &sU[(b) * 4096 + lbW[0]]);                      \
    gl16(gpU[1], &sU[(b) * 4096 + lbW[1]]);                      \
    gpX += 32; gpG[0] += 32; gpG[1] += 32; gpU[0] += 32; gpU[1] += 32; \
  } while (0)

  // prologue: fill 2 buffers
  S1_STAGE_ALL(0);
  S1_STAGE_ALL(1);
  VMW(5);
  BAR();

  const int fr = lane & 15, kb = lane >> 4;
  int cbo = 0, sbo = 2 * 4096;
#pragma unroll 1
  for (int kt = 0; kt < 24; ++kt) {
    const bool st = (kt <= 21);
    // ---- sub-phase 1: stage {X,G} || read A+G frags -> 8 G-MFMA ----
    if (st) {
      gl16(gpX, &sX[sbo + lbX]);
      gl16(gpG[0], &sG[sbo + lbW[0]]);
      gl16(gpG[1], &sG[sbo + lbW[1]]);
    }
    SCHEDB();
    bf16x8 a0 = RDB(sX, cbo, wm + fr, kb);
    bf16x8 a1 = RDB(sX, cbo, wm + 16 + fr, kb);
    bf16x8 a2 = RDB(sX, cbo, wm + 32 + fr, kb);
    bf16x8 a3 = RDB(sX, cbo, wm + 48 + fr, kb);
    bf16x8 g0 = RD8(sG, cbo, wn + fr, kb);
    bf16x8 g1 = RD8(sG, cbo, wn + 16 + fr, kb);
    BAR();
    PRIO(1);
    aG[0][0] = mfma(a0, g0, aG[0][0]);
    aG[1][0] = mfma(a1, g0, aG[1][0]);
    aG[2][0] = mfma(a2, g0, aG[2][0]);
    aG[3][0] = mfma(a3, g0, aG[3][0]);
    aG[0][1] = mfma(a0, g1, aG[0][1]);
    aG[1][1] = mfma(a1, g1, aG[1][1]);
    aG[2][1] = mfma(a2, g1, aG[2][1]);
    aG[3][1] = mfma(a3, g1, aG[3][1]);
    PRIO(0);
    BAR();
    // ---- sub-phase 2: stage {U} || read U frags -> 8 U-MFMA ----
    if (st) {
      gl16(gpU[0], &sU[sbo + lbW[0]]);
      gl16(gpU[1], &sU[sbo + lbW[1]]);
      gpX += 32; gpG[0] += 32; gpG[1] += 32; gpU[0] += 32; gpU[1] += 32;
    }
    SCHEDB();
    bf16x8 u0 = RD8(sU, cbo, wn + fr, kb);
    bf16x8 u1 = RD8(sU, cbo, wn + 16 + fr, kb);
    BAR();
    PRIO(1);
    aU[0][0] = mfma(a0, u0, aU[0][0]);
    aU[1][0] = mfma(a1, u0, aU[1][0]);
    aU[2][0] = mfma(a2, u0, aU[2][0]);
    aU[3][0] = mfma(a3, u0, aU[3][0]);
    aU[0][1] = mfma(a0, u1, aU[0][1]);
    aU[1][1] = mfma(a1, u1, aU[1][1]);
    aU[2][1] = mfma(a2, u1, aU[2][1]);
    aU[3][1] = mfma(a3, u1, aU[3][1]);
    PRIO(0);
    // ---- end of K-step: counted wait, never 0 until tail ----
    if (kt <= 21) { VMW(5); BAR(); }
    else if (kt == 22) { VMW(0); BAR(); }
    cbo = (cbo == 2 * 4096) ? 0 : cbo + 4096;
    sbo = (sbo == 2 * 4096) ? 0 : sbo + 4096;
  }

  // epilogue: C/D layout col=lane&15, row=(lane>>4)*4+reg
  const int crow = (lane >> 4) << 2;
  const int ccol = lane & 15;
#pragma unroll
  for (int mi = 0; mi < 4; ++mi) {
#pragma unroll
    for (int ri = 0; ri < 4; ++ri) {
      const int lm = wm + mi * 16 + crow + ri;
      if (lm < rows) {
        u16* hb = hbuf + (size_t)(r0 + lm) * HDIM + nt * 128 + wn;
#pragma unroll
        for (int nj = 0; nj < 2; ++nj) {
          const float g = aG[mi][nj][ri];
          const float u = aU[mi][nj][ri];
          const float h = g / (1.0f + __expf(-g)) * u;
          hb[nj * 16 + ccol] = f2bf(h);
        }
      }
    }
  }
}

// ---------------------------------------------------------------------------
// Stage 2: out[tok,:] += h Wd^T.  BM=128, BN=128, BK=32, split-K=2.
// grid = MAXT*12: bid = t*12 + ks*6 + nt. 512 thr = 8 waves (4M x 2N);
// wave = 32M x 64N. LDS: A 8KB + B 16KB per buffer x3 = 72KB.
// 32 K-steps (32*32 = 1024 = HDIM/2 per split); steady vmcnt(3).
// ---------------------------------------------------------------------------
__global__ __launch_bounds__(512, 1) void moe_stage2(
    const u16* __restrict__ hbuf, const int* __restrict__ perm,
    const int* __restrict__ meta, const float* __restrict__ wd,
    float* __restrict__ out) {
  const int t = blockIdx.x / 12;
  if (t >= meta[15]) return;
  const int rem = blockIdx.x - t * 12;
  const int ks = rem / 6;          // 0..1  (K halves of 2048)
  const int nt = rem - ks * 6;     // 0..5  (D columns nt*128)
  const int e = meta[16 + t];
  const int r0 = meta[48 + t];
  const int rows = min(128, meta[e + 1] - r0);

  __shared__ __align__(16) u16   sA[3 * 128 * 32];  // bf16
  __shared__ __align__(16) float sB[3 * 128 * 32];

  const int tid = threadIdx.x;
  const int lane = tid & 63;
  const int wv = tid >> 6;
  const int wm = (wv >> 1) * 32;  // 0,32,64,96
  const int wn = (wv & 1) * 64;   // 0,64

  // A staging (bf16): 1 gl16/thread; 16 rows x 4 chunks per instr
  const int ar = wv * 16 + (lane >> 2);
  const u16* gpA = hbuf + (size_t)(r0 + min(ar, rows - 1)) * HDIM + ks * 1024 +
                   (((lane & 3) ^ ((ar >> 1) & 3)) << 3);
  const int lbA = wv * 16 * 32;
  // B staging (fp32 Wd): 2 gl16/thread; 8 rows x 8 chunks per instr
  const int lr = lane >> 3, lc = lane & 7;
  const float* gpB[2];
  int lbB[2];
#pragma unroll
  for (int j = 0; j < 2; ++j) {
    const int r = wv * 16 + j * 8 + lr;
    gpB[j] = wd + ((size_t)e * DDIM + nt * 128 + r) * HDIM + ks * 1024 +
             ((lc ^ (r & 7)) << 2);
    lbB[j] = (wv * 16 + j * 8) * 32;
  }

  f32x4 acc[2][4] = {};

#define S2_STAGE_ALL(b) do {                                     \
    gl16(gpA, &sA[(b) * 4096 + lbA]);                            \
    gl16(gpB[0], &sB[(b) * 4096 + lbB[0]]);                      \
    gl16(gpB[1], &sB[(b) * 4096 + lbB[1]]);                      \
    gpA += 32; gpB[0] += 32; gpB[1] += 32;                       \
  } while (0)

  S2_STAGE_ALL(0);
  S2_STAGE_ALL(1);
  VMW(3);
  BAR();

  const int fr = lane & 15, kb = lane >> 4;
  int cbo = 0, sbo = 2 * 4096;
#pragma unroll 1
  for (int kt = 0; kt < 32; ++kt) {
    const bool st = (kt <= 29);
    // ---- sub-phase 1: stage {A,B0} || read A + B01 -> 4 MFMA ----
    if (st) {
      gl16(gpA, &sA[sbo + lbA]);
      gl16(gpB[0], &sB[sbo + lbB[0]]);
    }
    SCHEDB();
    bf16x8 a0 = RDB(sA, cbo, wm + fr, kb);
    bf16x8 a1 = RDB(sA, cbo, wm + 16 + fr, kb);
    bf16x8 b0 = RD8(sB, cbo, wn + fr, kb);
    bf16x8 b1 = RD8(sB, cbo, wn + 16 + fr, kb);
    BAR();
    PRIO(1);
    acc[0][0] = mfma(a0, b0, acc[0][0]);
    acc[1][0] = mfma(a1, b0, acc[1][0]);
    acc[0][1] = mfma(a0, b1, acc[0][1]);
    acc[1][1] = mfma(a1, b1, acc[1][1]);
    PRIO(0);
    BAR();
    // ---- sub-phase 2: stage {B1} || read B23 -> 4 MFMA ----
    if (st) {
      gl16(gpB[1], &sB[sbo + lbB[1]]);
      gpA += 32; gpB[0] += 32; gpB[1] += 32;
    }
    SCHEDB();
    bf16x8 b2 = RD8(sB, cbo, wn + 32 + fr, kb);
    bf16x8 b3 = RD8(sB, cbo, wn + 48 + fr, kb);
    BAR();
    PRIO(1);
    acc[0][2] = mfma(a0, b2, acc[0][2]);
    acc[1][2] = mfma(a1, b2, acc[1][2]);
    acc[0][3] = mfma(a0, b3, acc[0][3]);
    acc[1][3] = mfma(a1, b3, acc[1][3]);
    PRIO(0);
    if (kt <= 29) { VMW(3); BAR(); }
    else if (kt == 30) { VMW(0); BAR(); }
    cbo = (cbo == 2 * 4096) ? 0 : cbo + 4096;
    sbo = (sbo == 2 * 4096) ? 0 : sbo + 4096;
  }

  const int crow = (lane >> 4) << 2;
  const int ccol = lane & 15;
#pragma unroll
  for (int mi = 0; mi < 2; ++mi) {
#pragma unroll
    for (int ri = 0; ri < 4; ++ri) {
      const int lm = wm + mi * 16 + crow + ri;
      if (lm < rows) {
        const int tok = perm[r0 + lm];
        float* orow = out + (size_t)tok * DDIM + nt * 128 + wn;
#pragma unroll
        for (int nj = 0; nj < 4; ++nj) {
          atomicAdd(&orow[nj * 16 + ccol], acc[mi][nj][ri]);
        }
      }
    }
  }
}

// ---------------------------------------------------------------------------
extern "C" void kernel_launch(void* const* d_in, const int* in_sizes, int n_in,
                              void* d_out, int out_size, void* d_ws, size_t ws_size,
                              hipStream_t stream) {
  const float* x  = (const float*)d_in[0];
  const int* idx  = (const int*)d_in[1];
  const float* wg = (const float*)d_in[2];
  const float* wu = (const float*)d_in[3];
  const float* wd = (const float*)d_in[4];
  float* out = (float*)d_out;

  int* iws = (int*)d_ws;
  int* meta = iws;        // [0..8] offs, [15] ntiles, [16..47] e, [48..79] r0
  int* perm = iws + 128;  // 2048 ints
  u16* xbuf = (u16*)((char*)d_ws + 16384);              // 1024x768 bf16 = 1.5MB
  u16* hbuf = (u16*)((char*)d_ws + 16384 + (1 << 21));  // 2048x2048 bf16 = 8MB

  hipMemsetAsync(d_out, 0, (size_t)out_size * sizeof(float), stream);
  moe_cvtx<<<NTOK * DDIM / 2048, 256, 0, stream>>>(x, xbuf);
  moe_dispatch<<<1, 256, 0, stream>>>(idx, meta, perm);
  moe_stage1<<<MAXT * 16, 512, 0, stream>>>(xbuf, perm, meta, wg, wu, hbuf);
  moe_stage2<<<MAXT * 12, 512, 0, stream>>>(hbuf, perm, meta, wd, out);
}

// Round 10
// 159.128 us; speedup vs baseline: 1.1886x; 1.1886x over previous
//
#include <hip/hip_runtime.h>

// ---------------------------------------------------------------------------
// SwitchGLU MoE, round 10: weight-strip-persistent blocks, weights-once HBM.
//  - block = (expert-group, 32-col weight strip). Weights stream through LDS
//    in K-chunks of 128 (fp32->bf16 on the fly), fetched from HBM EXACTLY once
//    chip-wide. 2 barriers per chunk, 6 (s1) / 8 (s2) chunks total.
//  - X / h operands: direct global->register gathers (L2/L3-resident, no LDS,
//    no inter-wave coupling). Each wave owns up to 2 private 32-row M-tiles.
//  - small blocks (256 thr, 16-32 KB LDS) -> 12-16 waves/CU of TLP to hide
//    latency (the measured killer: 0.5-1.1 TB/s achieved on 64-79 MB fetch).
//  - R7-geometry 8B-chunk XOR swizzle (measured 0 conflicts).
// ---------------------------------------------------------------------------

typedef unsigned short u16;
typedef unsigned int   u32;
typedef u16    u16x8 __attribute__((ext_vector_type(8)));
typedef __bf16 bf16x8 __attribute__((ext_vector_type(8)));
typedef float  f32x4 __attribute__((ext_vector_type(4)));

#define NE   8
#define DDIM 768
#define HDIM 2048
#define NTOT 2048
#define NTOK 1024
#define MAXG 16

__device__ __forceinline__ u16 f2bf(float f) {
  return (u16)((__builtin_bit_cast(u32, f) + 0x8000u) >> 16);
}
// float4 -> 4 bf16 (8B) RNE via compiler v_cvt
__device__ __forceinline__ uint2 cvt2(float4 f) {
  union { u16 h[4]; uint2 v; } u;
  u.h[0] = __builtin_bit_cast(u16, (__bf16)f.x);
  u.h[1] = __builtin_bit_cast(u16, (__bf16)f.y);
  u.h[2] = __builtin_bit_cast(u16, (__bf16)f.z);
  u.h[3] = __builtin_bit_cast(u16, (__bf16)f.w);
  return u.v;
}
__device__ __forceinline__ bf16x8 cvt8(float4 a, float4 b) {
  bf16x8 r;
  r[0] = (__bf16)a.x; r[1] = (__bf16)a.y; r[2] = (__bf16)a.z; r[3] = (__bf16)a.w;
  r[4] = (__bf16)b.x; r[5] = (__bf16)b.y; r[6] = (__bf16)b.z; r[7] = (__bf16)b.w;
  return r;
}
// swizzled LDS frag read: tile rows of 64 u16; 8B chunk c0 ^= row&15 (R7 geom)
__device__ __forceinline__ bf16x8 ldsf(const u16* tile, int r, int c0) {
  const int key = r & 15;
  const u16* p = tile + r * 64;
  uint2 lo = *(const uint2*)(p + ((c0 ^ key) << 2));
  uint2 hi = *(const uint2*)(p + (((c0 + 1) ^ key) << 2));
  uint4 v = {lo.x, lo.y, hi.x, hi.y};
  return __builtin_bit_cast(bf16x8, v);
}
__device__ __forceinline__ bf16x8 ldg8(const u16* p) {
  return __builtin_bit_cast(bf16x8, *reinterpret_cast<const u16x8*>(p));
}
__device__ __forceinline__ f32x4 mfma(bf16x8 a, bf16x8 b, f32x4 c) {
  return __builtin_amdgcn_mfma_f32_16x16x32_bf16(a, b, c, 0, 0, 0);
}
#define SCHEDB()  __builtin_amdgcn_sched_barrier(0)
#define BAR()     __builtin_amdgcn_s_barrier()
#define WAITALL() asm volatile("s_waitcnt vmcnt(0) lgkmcnt(0)" ::: "memory")
#define WAITLGKM() asm volatile("s_waitcnt lgkmcnt(0)" ::: "memory")
#define WAITVM()  asm volatile("s_waitcnt vmcnt(0)" ::: "memory")

// ---------------------------------------------------------------------------
// x (fp32) -> xb (bf16). 384 blocks x 256 thr x 8 elems.
// ---------------------------------------------------------------------------
__global__ __launch_bounds__(256) void moe_cvtx(const float* __restrict__ x,
                                                u16* __restrict__ xb) {
  const int i = (blockIdx.x * 256 + threadIdx.x) * 8;
  const float4 f0 = *(const float4*)(x + i);
  const float4 f1 = *(const float4*)(x + i + 4);
  *(uint4*)(xb + i) = __builtin_bit_cast(uint4, cvt8(f0, f1));
}

// ---------------------------------------------------------------------------
// Dispatch: bucket pairs by expert + 256-row group table.
// meta: [0..8]=offs, [15]=ngroups, [16+g]=e, [48+g]=r0, [80+g]=rows.
// ---------------------------------------------------------------------------
__global__ void moe_dispatch(const int* __restrict__ idx,
                             int* __restrict__ meta, int* __restrict__ perm) {
  __shared__ int s_cnt[NE];
  __shared__ int s_off[NE + 1];
  __shared__ int s_cur[NE];
  const int tid = threadIdx.x;
  if (tid < NE) { s_cnt[tid] = 0; s_cur[tid] = 0; }
  __syncthreads();
  for (int n = tid; n < NTOT; n += 256) atomicAdd(&s_cnt[idx[n]], 1);
  __syncthreads();
  if (tid == 0) {
    int a = 0;
    for (int e = 0; e < NE; ++e) { s_off[e] = a; a += s_cnt[e]; }
    s_off[NE] = a;
  }
  __syncthreads();
  for (int n = tid; n < NTOT; n += 256) {
    const int e = idx[n];
    perm[s_off[e] + atomicAdd(&s_cur[e], 1)] = n;
  }
  if (tid == 0) {
    int gc = 0;
    for (int e = 0; e < NE; ++e) {
      for (int r0 = s_off[e]; r0 < s_off[e + 1]; r0 += 256) {
        meta[16 + gc] = e;
        meta[48 + gc] = r0;
        meta[80 + gc] = min(256, s_off[e + 1] - r0);
        ++gc;
      }
    }
    meta[15] = gc;
  }
  if (tid < NE + 1) meta[tid] = s_off[tid];
}

// ---------------------------------------------------------------------------
// Stage 1: h = silu(X Wg^T) * (X Wu^T).
// grid = MAXG*64: block = (group g, H-strip of 32). 256 thr = 4 waves.
// Wave owns M-tiles {wv, wv+4} of 32 rows (acc in regs). Weights stream
// through LDS in 6 K-chunks of 128 (dbuf, 32 KB total).
// ---------------------------------------------------------------------------
__global__ __launch_bounds__(256, 3) void moe_stage1(
    const u16* __restrict__ xb, const int* __restrict__ perm,
    const int* __restrict__ meta, const float* __restrict__ wg,
    const float* __restrict__ wu, u16* __restrict__ hbuf) {
  const int g = blockIdx.x >> 6;
  if (g >= meta[15]) return;
  const int strip = blockIdx.x & 63;  // H cols strip*32
  const int e    = meta[16 + g];
  const int r0   = meta[48 + g];
  const int rows = meta[80 + g];

  // [buf2][kseg2][32 rows * 64 u16] = 16 KB each
  __shared__ __align__(16) u16 sG[2 * 2 * 2048];
  __shared__ __align__(16) u16 sU[2 * 2 * 2048];

  const int tid = threadIdx.x;
  const int lane = tid & 63;
  const int wv = tid >> 6;
  const int fr = lane & 15, kb = lane >> 4;

  // weight staging map: thread -> (row srow, 16-float seg sseg)
  const int srow = tid >> 3, sseg = tid & 7;
  const float* gp = wg + ((size_t)e * HDIM + strip * 32 + srow) * DDIM + sseg * 16;
  const float* up = wu + ((size_t)e * HDIM + strip * 32 + srow) * DDIM + sseg * 16;

  // M-tile slots
  const int m0 = wv * 32;
  const int m1 = (wv + 4) * 32;
  const bool act0 = m0 < rows;
  const bool act1 = m1 < rows;
  const u16 *ap00, *ap01, *ap10, *ap11;
  {
    const int q00 = min(m0 + fr, rows - 1);
    const int q01 = min(m0 + 16 + fr, rows - 1);
    const int q10 = min(m1 + fr, rows - 1);
    const int q11 = min(m1 + 16 + fr, rows - 1);
    ap00 = xb + (size_t)(perm[r0 + q00] >> 1) * DDIM + kb * 8;
    ap01 = xb + (size_t)(perm[r0 + q01] >> 1) * DDIM + kb * 8;
    ap10 = xb + (size_t)(perm[r0 + q10] >> 1) * DDIM + kb * 8;
    ap11 = xb + (size_t)(perm[r0 + q11] >> 1) * DDIM + kb * 8;
  }

  f32x4 aG[2][2][2] = {};  // [slot][mi][nj]
  f32x4 aU[2][2][2] = {};
  float4 lg[4], lu[4];

#define S1_LOAD(c) do {                                              \
    const float4* q_;                                                \
    q_ = (const float4*)(gp + (c) * 128);                            \
    lg[0] = q_[0]; lg[1] = q_[1]; lg[2] = q_[2]; lg[3] = q_[3];      \
    q_ = (const float4*)(up + (c) * 128);                            \
    lu[0] = q_[0]; lu[1] = q_[1]; lu[2] = q_[2]; lu[3] = q_[3];      \
  } while (0)

#define S1_WRITE(b) do {                                                       \
    _Pragma("unroll") for (int j = 0; j < 4; ++j) {                            \
      const int ca = sseg * 4 + j;                                             \
      const int off = (b) * 4096 + (ca >> 4) * 2048 + srow * 64 +              \
                      (((ca & 15) ^ (srow & 15)) << 2);                        \
      *(uint2*)&sG[off] = cvt2(lg[j]);                                         \
      *(uint2*)&sU[off] = cvt2(lu[j]);                                         \
    }                                                                          \
  } while (0)

#define S1_COMPUTE(bufo, c) do {                                               \
    _Pragma("unroll") for (int ks = 0; ks < 4; ++ks) {                         \
      const u16* gb = &sG[(bufo) + (ks >> 1) * 2048];                          \
      const u16* ub = &sU[(bufo) + (ks >> 1) * 2048];                          \
      const int c0 = (ks & 1) * 8 + kb * 2;                                    \
      const bf16x8 g0 = ldsf(gb, fr, c0);                                      \
      const bf16x8 g1 = ldsf(gb, 16 + fr, c0);                                 \
      const bf16x8 u0 = ldsf(ub, fr, c0);                                      \
      const bf16x8 u1 = ldsf(ub, 16 + fr, c0);                                 \
      const int ko = (c) * 128 + ks * 32;                                      \
      if (act0) {                                                              \
        const bf16x8 a0 = ldg8(ap00 + ko);                                     \
        const bf16x8 a1 = ldg8(ap01 + ko);                                     \
        aG[0][0][0] = mfma(a0, g0, aG[0][0][0]);                               \
        aG[0][1][0] = mfma(a1, g0, aG[0][1][0]);                               \
        aG[0][0][1] = mfma(a0, g1, aG[0][0][1]);                               \
        aG[0][1][1] = mfma(a1, g1, aG[0][1][1]);                               \
        aU[0][0][0] = mfma(a0, u0, aU[0][0][0]);                               \
        aU[0][1][0] = mfma(a1, u0, aU[0][1][0]);                               \
        aU[0][0][1] = mfma(a0, u1, aU[0][0][1]);                               \
        aU[0][1][1] = mfma(a1, u1, aU[0][1][1]);                               \
      }                                                                        \
      if (act1) {                                                              \
        const bf16x8 a0 = ldg8(ap10 + ko);                                     \
        const bf16x8 a1 = ldg8(ap11 + ko);                                     \
        aG[1][0][0] = mfma(a0, g0, aG[1][0][0]);                               \
        aG[1][1][0] = mfma(a1, g0, aG[1][1][0]);                               \
        aG[1][0][1] = mfma(a0, g1, aG[1][0][1]);                               \
        aG[1][1][1] = mfma(a1, g1, aG[1][1][1]);                               \
        aU[1][0][0] = mfma(a0, u0, aU[1][0][0]);                               \
        aU[1][1][0] = mfma(a1, u0, aU[1][1][0]);                               \
        aU[1][0][1] = mfma(a0, u1, aU[1][0][1]);                               \
        aU[1][1][1] = mfma(a1, u1, aU[1][1][1]);                               \
      }                                                                        \
    }                                                                          \
  } while (0)

  S1_LOAD(0);
  WAITVM();
  SCHEDB();
  S1_WRITE(0);
  WAITLGKM();
  BAR();

#pragma unroll 1
  for (int c = 0; c < 6; ++c) {
    if (c < 5) S1_LOAD(c + 1);
    SCHEDB();
    S1_COMPUTE((c & 1) * 4096, c);
    SCHEDB();
    WAITALL();
    BAR();
    if (c < 5) {
      S1_WRITE((c + 1) & 1);
      WAITLGKM();
      BAR();
    }
  }

  // epilogue: C/D col=lane&15, row=(lane>>4)*4+reg
  const int crow = kb * 4, ccol = fr;
#pragma unroll
  for (int s = 0; s < 2; ++s) {
    const bool act = s ? act1 : act0;
    const int mb = s ? m1 : m0;
    if (!act) continue;
#pragma unroll
    for (int mi = 0; mi < 2; ++mi) {
#pragma unroll
      for (int ri = 0; ri < 4; ++ri) {
        const int lm = mb + mi * 16 + crow + ri;
        if (lm < rows) {
          u16* hb = hbuf + (size_t)(r0 + lm) * HDIM + strip * 32;
#pragma unroll
          for (int nj = 0; nj < 2; ++nj) {
            const float gv = aG[s][mi][nj][ri];
            const float uv = aU[s][mi][nj][ri];
            const float h = gv / (1.0f + __expf(-gv)) * uv;
            hb[nj * 16 + ccol] = f2bf(h);
          }
        }
      }
    }
  }
}

// ---------------------------------------------------------------------------
// Stage 2: out[tok,:] += h Wd^T.  split-K=2 over HDIM halves.
// grid = MAXG*48: block = (group g, D-strip of 32, ks). 256 thr = 4 waves.
// Wd strip streams through LDS in 8 K-chunks of 128 (16 KB).
// ---------------------------------------------------------------------------
__global__ __launch_bounds__(256, 4) void moe_stage2(
    const u16* __restrict__ hbuf, const int* __restrict__ perm,
    const int* __restrict__ meta, const float* __restrict__ wd,
    float* __restrict__ out) {
  const int g = blockIdx.x / 48;
  if (g >= meta[15]) return;
  const int rem = blockIdx.x - g * 48;
  const int ks = rem / 24;          // 0..1
  const int strip = rem - ks * 24;  // 0..23 (D cols strip*32)
  const int e    = meta[16 + g];
  const int r0   = meta[48 + g];
  const int rows = meta[80 + g];

  __shared__ __align__(16) u16 sB[2 * 2 * 2048];  // 16 KB

  const int tid = threadIdx.x;
  const int lane = tid & 63;
  const int wv = tid >> 6;
  const int fr = lane & 15, kb = lane >> 4;

  const int srow = tid >> 3, sseg = tid & 7;
  const float* bp = wd + ((size_t)e * DDIM + strip * 32 + srow) * HDIM +
                    ks * 1024 + sseg * 16;

  const int m0 = wv * 32;
  const int m1 = (wv + 4) * 32;
  const bool act0 = m0 < rows;
  const bool act1 = m1 < rows;
  const u16 *ap00, *ap01, *ap10, *ap11;
  {
    const int q00 = min(m0 + fr, rows - 1);
    const int q01 = min(m0 + 16 + fr, rows - 1);
    const int q10 = min(m1 + fr, rows - 1);
    const int q11 = min(m1 + 16 + fr, rows - 1);
    ap00 = hbuf + (size_t)(r0 + q00) * HDIM + ks * 1024 + kb * 8;
    ap01 = hbuf + (size_t)(r0 + q01) * HDIM + ks * 1024 + kb * 8;
    ap10 = hbuf + (size_t)(r0 + q10) * HDIM + ks * 1024 + kb * 8;
    ap11 = hbuf + (size_t)(r0 + q11) * HDIM + ks * 1024 + kb * 8;
  }

  f32x4 ac[2][2][2] = {};  // [slot][mi][nj]
  float4 lb[4];

#define S2_LOAD(c) do {                                              \
    const float4* q_ = (const float4*)(bp + (c) * 128);              \
    lb[0] = q_[0]; lb[1] = q_[1]; lb[2] = q_[2]; lb[3] = q_[3];      \
  } while (0)

#define S2_WRITE(b) do {                                                       \
    _Pragma("unroll") for (int j = 0; j < 4; ++j) {                            \
      const int ca = sseg * 4 + j;                                             \
      const int off = (b) * 4096 + (ca >> 4) * 2048 + srow * 64 +              \
                      (((ca & 15) ^ (srow & 15)) << 2);                        \
      *(uint2*)&sB[off] = cvt2(lb[j]);                                         \
    }                                                                          \
  } while (0)

#define S2_COMPUTE(bufo, c) do {                                               \
    _Pragma("unroll") for (int ks2 = 0; ks2 < 4; ++ks2) {                      \
      const u16* bb = &sB[(bufo) + (ks2 >> 1) * 2048];                         \
      const int c0 = (ks2 & 1) * 8 + kb * 2;                                   \
      const bf16x8 b0 = ldsf(bb, fr, c0);                                      \
      const bf16x8 b1 = ldsf(bb, 16 + fr, c0);                                 \
      const int ko = (c) * 128 + ks2 * 32;                                     \
      if (act0) {                                                              \
        const bf16x8 a0 = ldg8(ap00 + ko);                                     \
        const bf16x8 a1 = ldg8(ap01 + ko);                                     \
        ac[0][0][0] = mfma(a0, b0, ac[0][0][0]);                               \
        ac[0][1][0] = mfma(a1, b0, ac[0][1][0]);                               \
        ac[0][0][1] = mfma(a0, b1, ac[0][0][1]);                               \
        ac[0][1][1] = mfma(a1, b1, ac[0][1][1]);                               \
      }                                                                        \
      if (act1) {                                                              \
        const bf16x8 a0 = ldg8(ap10 + ko);                                     \
        const bf16x8 a1 = ldg8(ap11 + ko);                                     \
        ac[1][0][0] = mfma(a0, b0, ac[1][0][0]);                               \
        ac[1][1][0] = mfma(a1, b0, ac[1][1][0]);                               \
        ac[1][0][1] = mfma(a0, b1, ac[1][0][1]);                               \
        ac[1][1][1] = mfma(a1, b1, ac[1][1][1]);                               \
      }                                                                        \
    }                                                                          \
  } while (0)

  S2_LOAD(0);
  WAITVM();
  SCHEDB();
  S2_WRITE(0);
  WAITLGKM();
  BAR();

#pragma unroll 1
  for (int c = 0; c < 8; ++c) {
    if (c < 7) S2_LOAD(c + 1);
    SCHEDB();
    S2_COMPUTE((c & 1) * 4096, c);
    SCHEDB();
    WAITALL();
    BAR();
    if (c < 7) {
      S2_WRITE((c + 1) & 1);
      WAITLGKM();
      BAR();
    }
  }

  const int crow = kb * 4, ccol = fr;
#pragma unroll
  for (int s = 0; s < 2; ++s) {
    const bool act = s ? act1 : act0;
    const int mb = s ? m1 : m0;
    if (!act) continue;
#pragma unroll
    for (int mi = 0; mi < 2; ++mi) {
#pragma unroll
      for (int ri = 0; ri < 4; ++ri) {
        const int lm = mb + mi * 16 + crow + ri;
        if (lm < rows) {
          const int tok = perm[r0 + lm];
          float* orow = out + (size_t)tok * DDIM + strip * 32;
#pragma unroll
          for (int nj = 0; nj < 2; ++nj) {
            atomicAdd(&orow[nj * 16 + ccol], ac[s][mi][nj][ri]);
          }
        }
      }
    }
  }
}

// ---------------------------------------------------------------------------
extern "C" void kernel_launch(void* const* d_in, const int* in_sizes, int n_in,
                              void* d_out, int out_size, void* d_ws, size_t ws_size,
                              hipStream_t stream) {
  const float* x  = (const float*)d_in[0];
  const int* idx  = (const int*)d_in[1];
  const float* wg = (const float*)d_in[2];
  const float* wu = (const float*)d_in[3];
  const float* wd = (const float*)d_in[4];
  float* out = (float*)d_out;

  int* iws = (int*)d_ws;
  int* meta = iws;        // [0..8] offs, [15] ngroups, [16..]e, [48..]r0, [80..]rows
  int* perm = iws + 128;  // 2048 ints
  u16* xbuf = (u16*)((char*)d_ws + 16384);              // 1024x768 bf16
  u16* hbuf = (u16*)((char*)d_ws + 16384 + (1 << 21));  // 2048x2048 bf16

  hipMemsetAsync(d_out, 0, (size_t)out_size * sizeof(float), stream);
  moe_cvtx<<<NTOK * DDIM / 2048, 256, 0, stream>>>(x, xbuf);
  moe_dispatch<<<1, 256, 0, stream>>>(idx, meta, perm);
  moe_stage1<<<MAXG * 64, 256, 0, stream>>>(xbuf, perm, meta, wg, wu, hbuf);
  moe_stage2<<<MAXG * 48, 256, 0, stream>>>(hbuf, perm, meta, wd, out);
}